// Round 5
// baseline (1686.300 us; speedup 1.0000x reference)
//
#include <hip/hip_runtime.h>
#include <hip/hip_bf16.h>
#include <hip/hip_fp16.h>
#include <math.h>

#define DH 10      // hidden dim
#define DE 3       // edge attr dim
#define DIN 3      // input dim
#define REC 20     // fp32 D record: 20 floats = 80B
#define SHU 12     // fp16 S record stride in uints (24 halves = 48B, 10 used)
#define VEC 4      // lanes cooperating per node in gather
#define BATCH 4    // edges in flight per lane

typedef unsigned int u32;
typedef float f4v __attribute__((ext_vector_type(4)));

__device__ __forceinline__ u32 pack_h2(float a, float b) {
    union { __half2 h; u32 u; } cv;
    cv.h = __floats2half2_rn(a, b);
    return cv.u;
}

// ---------------------------------------------------------------------------
// Per-node records. D (fp32, dst side, biases folded): {fb + h@fWd.T, sb + h@sWd.T}
// S (fp16 packed, src side): {h@fWs.T, h@sWs.T} as 10 half2 words.
// ---------------------------------------------------------------------------
__device__ __forceinline__ void compute_records_h(
    const float* __restrict__ hh,
    const float* __restrict__ fW, const float* __restrict__ fb,
    const float* __restrict__ sW, const float* __restrict__ sb,
    float* __restrict__ Dout, u32* __restrict__ Sout)
{
    float fsv[DH], ssv[DH];
#pragma unroll
    for (int j = 0; j < DH; ++j) {
        float fd = fb[j], sd = sb[j], fs = 0.f, ss = 0.f;
#pragma unroll
        for (int k = 0; k < DH; ++k) {
            fd += hh[k] * fW[j*23 + k];
            fs += hh[k] * fW[j*23 + 10 + k];
            sd += hh[k] * sW[j*23 + k];
            ss += hh[k] * sW[j*23 + 10 + k];
        }
        Dout[j]      = fd;
        Dout[DH + j] = sd;
        fsv[j] = fs;
        ssv[j] = ss;
    }
#pragma unroll
    for (int j = 0; j < 5; ++j) {
        Sout[j]     = pack_h2(fsv[2*j], fsv[2*j+1]);
        Sout[5 + j] = pack_h2(ssv[2*j], ssv[2*j+1]);
    }
}

// fp32 variant for the fallback path
__device__ __forceinline__ void compute_records(
    const float* __restrict__ hh,
    const float* __restrict__ fW, const float* __restrict__ fb,
    const float* __restrict__ sW, const float* __restrict__ sb,
    float* __restrict__ Dout, float* __restrict__ Sout)
{
#pragma unroll
    for (int j = 0; j < DH; ++j) {
        float fd = fb[j], sd = sb[j], fs = 0.f, ss = 0.f;
#pragma unroll
        for (int k = 0; k < DH; ++k) {
            fd += hh[k] * fW[j*23 + k];
            fs += hh[k] * fW[j*23 + 10 + k];
            sd += hh[k] * sW[j*23 + k];
            ss += hh[k] * sW[j*23 + 10 + k];
        }
        Dout[j]      = fd;
        Dout[DH + j] = sd;
        Sout[j]      = fs;
        Sout[DH + j] = ss;
    }
}

// ---------------------------------------------------------------------------
// P0 (csr path): h0 = relu(x@preW.T+preb); layer-1 records; zero deg/gsum/gcnt
// ---------------------------------------------------------------------------
__global__ void node_pre_h(const float* __restrict__ x,
                           const float* __restrict__ preW, const float* __restrict__ preb,
                           const float* __restrict__ fW, const float* __restrict__ fb,
                           const float* __restrict__ sW, const float* __restrict__ sb,
                           float* __restrict__ h, float* __restrict__ D, u32* __restrict__ Sh,
                           int* __restrict__ deg,
                           float* __restrict__ gsum, float* __restrict__ gcnt, int N, int G)
{
    __shared__ float lpW[30], lpb[10], lfW[230], lfb[10], lsW[230], lsb[10];
    for (int i = threadIdx.x; i < 30;  i += blockDim.x) lpW[i] = preW[i];
    for (int i = threadIdx.x; i < 10;  i += blockDim.x) { lpb[i] = preb[i]; lfb[i] = fb[i]; lsb[i] = sb[i]; }
    for (int i = threadIdx.x; i < 230; i += blockDim.x) { lfW[i] = fW[i]; lsW[i] = sW[i]; }
    __syncthreads();

    int n = blockIdx.x * blockDim.x + threadIdx.x;
    if (n < G * DH) gsum[n] = 0.f;
    if (n < G)      gcnt[n] = 0.f;
    if (n >= N) return;
    deg[n] = 0;

    float x0 = x[(size_t)n*3], x1 = x[(size_t)n*3+1], x2 = x[(size_t)n*3+2];
    float hh[DH];
#pragma unroll
    for (int j = 0; j < DH; ++j)
        hh[j] = fmaxf(lpb[j] + x0*lpW[j*3] + x1*lpW[j*3+1] + x2*lpW[j*3+2], 0.f);

    float* hp = h + (size_t)n * DH;
#pragma unroll
    for (int j = 0; j < DH; ++j) hp[j] = hh[j];

    compute_records_h(hh, lfW, lfb, lsW, lsb, D + (size_t)n*REC, Sh + (size_t)n*SHU);
}

// ---------------------------------------------------------------------------
// CSR build: histogram, 3-kernel exclusive scan, scatter
// ---------------------------------------------------------------------------
__global__ void hist_kernel(const int* __restrict__ ei, int* __restrict__ deg, int E)
{
    int e = blockIdx.x * blockDim.x + threadIdx.x;
    if (e < E) atomicAdd(&deg[__builtin_nontemporal_load(ei + (size_t)E + e)], 1);
}

__global__ void scan_block(const int* __restrict__ deg, int* __restrict__ excl,
                           int* __restrict__ bsum, int N)
{
    __shared__ int s[256];
    int tid = threadIdx.x;
    int n = blockIdx.x * 256 + tid;
    int v = (n < N) ? deg[n] : 0;
    s[tid] = v;
    __syncthreads();
#pragma unroll
    for (int off = 1; off < 256; off <<= 1) {
        int t = (tid >= off) ? s[tid - off] : 0;
        __syncthreads();
        if (tid >= off) s[tid] += t;
        __syncthreads();
    }
    if (n < N) excl[n] = s[tid] - v;
    if (tid == 255) bsum[blockIdx.x] = s[255];
}

__global__ void scan_sums(int* __restrict__ bsum, int B)   // exclusive, in place
{
    __shared__ int s[1024];
    int tid = threadIdx.x;
    int v = (tid < B) ? bsum[tid] : 0;
    s[tid] = v;
    __syncthreads();
#pragma unroll
    for (int off = 1; off < 1024; off <<= 1) {
        int t = (tid >= off) ? s[tid - off] : 0;
        __syncthreads();
        if (tid >= off) s[tid] += t;
        __syncthreads();
    }
    if (tid < B) bsum[tid] = s[tid] - v;
}

__global__ void scan_add(int* __restrict__ rowptr, const int* __restrict__ bsum,
                         int* __restrict__ head, int N, int E)
{
    int n = blockIdx.x * blockDim.x + threadIdx.x;
    if (n < N) {
        int r = rowptr[n] + bsum[n >> 8];
        rowptr[n] = r;
        head[n] = r;
    }
    if (n == 0) rowptr[N] = E;
}

__global__ void scatter_csr(const int* __restrict__ ei, const float* __restrict__ attr,
                            int* __restrict__ head, float4* __restrict__ csr, int E)
{
    int e = blockIdx.x * blockDim.x + threadIdx.x;
    if (e >= E) return;
    int src = __builtin_nontemporal_load(ei + e);
    int dst = __builtin_nontemporal_load(ei + (size_t)E + e);
    float a0 = __builtin_nontemporal_load(attr + (size_t)e * DE);
    float a1 = __builtin_nontemporal_load(attr + (size_t)e * DE + 1);
    float a2 = __builtin_nontemporal_load(attr + (size_t)e * DE + 2);
    int pos = atomicAdd(&head[dst], 1);
    csr[pos] = make_float4(__int_as_float(src), a0, a1, a2);
}

// ---------------------------------------------------------------------------
// Gather aggregation. VEC=4 lanes/node; each lane owns a CONTIGUOUS run of
// its node's CSR slots and keeps BATCH=4 edges in flight (4 independent csr
// dwordx4 -> 12 independent scattered srec loads -> compute 4 edges).
// ---------------------------------------------------------------------------
struct SRecP { uint4 A, B; uint2 C; };

__device__ __forceinline__ SRecP load_srec(const u32* __restrict__ ShU, int src)
{
    const uint4* sp = (const uint4*)(ShU + (size_t)src * SHU);
    SRecP r;
    r.A = sp[0];
    r.B = sp[1];
    r.C = *(const uint2*)(sp + 2);
    return r;
}

__device__ __forceinline__ void compute_edge(
    f4v c, const SRecP& r, const float* __restrict__ drec,
    const float* __restrict__ wf, const float* __restrict__ wsr,
    float* __restrict__ acc)
{
    u32 u[10] = {r.A.x, r.A.y, r.A.z, r.A.w, r.B.x, r.B.y, r.B.z, r.B.w, r.C.x, r.C.y};
    float s[20];
#pragma unroll
    for (int i = 0; i < 10; ++i) {
        union { u32 u; __half2 h; } cv; cv.u = u[i];
        float2 f = __half22float2(cv.h);
        s[2*i] = f.x; s[2*i+1] = f.y;
    }
#pragma unroll
    for (int j = 0; j < DH; ++j) {
        float pf = drec[j]      + s[j]      + c.y*wf[j*3]  + c.z*wf[j*3+1]  + c.w*wf[j*3+2];
        float ps = drec[DH + j] + s[DH + j] + c.y*wsr[j*3] + c.z*wsr[j*3+1] + c.w*wsr[j*3+2];
        float sg = __builtin_amdgcn_rcpf(1.0f + __expf(-pf));          // sigmoid
        float sp = fmaxf(ps, 0.f) + __logf(1.0f + __expf(-fabsf(ps))); // softplus
        acc[j] += sg * sp;
    }
}

__global__ __launch_bounds__(256) void gather_agg4(
    const int* __restrict__ rowptr, const float4* __restrict__ csr,
    const float* __restrict__ D, const u32* __restrict__ ShU,
    const float* __restrict__ Wf, const float* __restrict__ Ws,
    float* __restrict__ h, int N,
    const int* __restrict__ batch,
    float* __restrict__ gsum, float* __restrict__ gcnt, int do_pool)
{
    // uniform edge-column weights -> scalar (SGPR) after unroll
    float wf[30], wsr[30];
#pragma unroll
    for (int i = 0; i < 30; ++i) {
        int j = i / 3, t = i % 3;
        wf[i]  = Wf[j*23 + 20 + t];
        wsr[i] = Ws[j*23 + 20 + t];
    }

    int tid = blockIdx.x * blockDim.x + threadIdx.x;
    int n   = tid >> 2;
    int sub = tid & (VEC - 1);
    if (n >= N) return;

    float drec[REC];
    const float4* Dp = (const float4*)(D + (size_t)n * REC);
#pragma unroll
    for (int i = 0; i < 5; ++i) ((float4*)drec)[i] = Dp[i];

    float acc[DH];
#pragma unroll
    for (int j = 0; j < DH; ++j) acc[j] = 0.f;

    const f4v* cp = (const f4v*)csr;
    int p0  = rowptr[n];
    int p1  = rowptr[n + 1];
    int q   = (p1 - p0 + VEC - 1) >> 2;          // slots per lane
    int p   = p0 + sub * q;                      // my contiguous run
    int lend = p + q; if (lend > p1) lend = p1;

    for (; p + BATCH <= lend; p += BATCH) {
        f4v   c[BATCH];
        SRecP r[BATCH];
#pragma unroll
        for (int i = 0; i < BATCH; ++i) c[i] = __builtin_nontemporal_load(cp + p + i);
#pragma unroll
        for (int i = 0; i < BATCH; ++i) r[i] = load_srec(ShU, __float_as_int(c[i].x));
#pragma unroll
        for (int i = 0; i < BATCH; ++i) compute_edge(c[i], r[i], drec, wf, wsr, acc);
    }
    for (; p < lend; ++p) {
        f4v c0 = __builtin_nontemporal_load(cp + p);
        SRecP r0 = load_srec(ShU, __float_as_int(c0.x));
        compute_edge(c0, r0, drec, wf, wsr, acc);
    }

    // butterfly reduce across the 4 lanes of this node
#pragma unroll
    for (int j = 0; j < DH; ++j) {
        acc[j] += __shfl_xor(acc[j], 1);
        acc[j] += __shfl_xor(acc[j], 2);
    }

    if (sub == 0) {
        float* hp = h + (size_t)n * DH;
        float hh[DH];
#pragma unroll
        for (int j = 0; j < DH; ++j) hh[j] = fmaxf(hp[j] + acc[j], 0.f);
        if (do_pool) {
            int b = batch[n];
            float* gp = gsum + (size_t)b * DH;
#pragma unroll
            for (int j = 0; j < DH; ++j) atomicAdd(gp + j, hh[j]);
            atomicAdd(gcnt + b, 1.f);
        } else {
#pragma unroll
            for (int j = 0; j < DH; ++j) hp[j] = hh[j];
        }
    }
}

// Records for layer 2 from h1
__global__ void node_rec_h(const float* __restrict__ h,
                           const float* __restrict__ fW, const float* __restrict__ fb,
                           const float* __restrict__ sW, const float* __restrict__ sb,
                           float* __restrict__ D, u32* __restrict__ Sh, int N)
{
    __shared__ float lfW[230], lfb[10], lsW[230], lsb[10];
    for (int i = threadIdx.x; i < 230; i += blockDim.x) { lfW[i] = fW[i]; lsW[i] = sW[i]; }
    for (int i = threadIdx.x; i < 10;  i += blockDim.x) { lfb[i] = fb[i]; lsb[i] = sb[i]; }
    __syncthreads();
    int n = blockIdx.x * blockDim.x + threadIdx.x;
    if (n >= N) return;
    float hh[DH];
    const float* hp = h + (size_t)n * DH;
#pragma unroll
    for (int j = 0; j < DH; ++j) hh[j] = hp[j];
    compute_records_h(hh, lfW, lfb, lsW, lsb, D + (size_t)n*REC, Sh + (size_t)n*SHU);
}

// ---------------------------------------------------------------------------
// Fallback path kernels (fp32 everything; used only if ws too small)
// ---------------------------------------------------------------------------
__global__ void node_pre_f32(const float* __restrict__ x,
                             const float* __restrict__ preW, const float* __restrict__ preb,
                             const float* __restrict__ fW, const float* __restrict__ fb,
                             const float* __restrict__ sW, const float* __restrict__ sb,
                             float* __restrict__ h, float* __restrict__ D, float* __restrict__ S,
                             float* __restrict__ agg,
                             float* __restrict__ gsum, float* __restrict__ gcnt, int N, int G)
{
    __shared__ float lpW[30], lpb[10], lfW[230], lfb[10], lsW[230], lsb[10];
    for (int i = threadIdx.x; i < 30;  i += blockDim.x) lpW[i] = preW[i];
    for (int i = threadIdx.x; i < 10;  i += blockDim.x) { lpb[i] = preb[i]; lfb[i] = fb[i]; lsb[i] = sb[i]; }
    for (int i = threadIdx.x; i < 230; i += blockDim.x) { lfW[i] = fW[i]; lsW[i] = sW[i]; }
    __syncthreads();
    int n = blockIdx.x * blockDim.x + threadIdx.x;
    if (n < G * DH) gsum[n] = 0.f;
    if (n < G)      gcnt[n] = 0.f;
    if (n >= N) return;
    float x0 = x[(size_t)n*3], x1 = x[(size_t)n*3+1], x2 = x[(size_t)n*3+2];
    float hh[DH];
#pragma unroll
    for (int j = 0; j < DH; ++j)
        hh[j] = fmaxf(lpb[j] + x0*lpW[j*3] + x1*lpW[j*3+1] + x2*lpW[j*3+2], 0.f);
    float* hp = h + (size_t)n * DH;
    float* ap = agg + (size_t)n * DH;
#pragma unroll
    for (int j = 0; j < DH; ++j) { hp[j] = hh[j]; ap[j] = 0.f; }
    compute_records(hh, lfW, lfb, lsW, lsb, D + (size_t)n*REC, S + (size_t)n*REC);
}

__global__ void edge_pass(const int* __restrict__ ei, const float* __restrict__ attr,
                          const float* __restrict__ D, const float* __restrict__ S,
                          const float* __restrict__ Wf, const float* __restrict__ Ws,
                          float* __restrict__ agg, int E)
{
    __shared__ float wfe[30], wse[30];
    if (threadIdx.x < 30) {
        int j = threadIdx.x / 3, t = threadIdx.x % 3;
        wfe[threadIdx.x] = Wf[j*23 + 20 + t];
        wse[threadIdx.x] = Ws[j*23 + 20 + t];
    }
    __syncthreads();
    int e = blockIdx.x * blockDim.x + threadIdx.x;
    if (e >= E) return;
    int src = ei[e];
    int dst = ei[(size_t)E + e];
    const float* eap = attr + (size_t)e * DE;
    float ea0 = eap[0], ea1 = eap[1], ea2 = eap[2];
    float drec[REC], srec[REC];
    const float4* Dp = (const float4*)(D + (size_t)dst * REC);
    const float4* Sp = (const float4*)(S + (size_t)src * REC);
#pragma unroll
    for (int i = 0; i < 5; ++i) { ((float4*)drec)[i] = Dp[i]; ((float4*)srec)[i] = Sp[i]; }
    float* ap = agg + (size_t)dst * DH;
#pragma unroll
    for (int j = 0; j < DH; ++j) {
        float pf = drec[j]      + srec[j]      + ea0*wfe[j*3] + ea1*wfe[j*3+1] + ea2*wfe[j*3+2];
        float ps = drec[DH + j] + srec[DH + j] + ea0*wse[j*3] + ea1*wse[j*3+1] + ea2*wse[j*3+2];
        float sg = 1.0f / (1.0f + __expf(-pf));
        float sp = fmaxf(ps, 0.f) + log1pf(__expf(-fabsf(ps)));
        atomicAdd(ap + j, sg * sp);
    }
}

__global__ void node_mid(float* __restrict__ h, float* __restrict__ agg,
                         const float* __restrict__ fW, const float* __restrict__ fb,
                         const float* __restrict__ sW, const float* __restrict__ sb,
                         float* __restrict__ D, float* __restrict__ S, int N)
{
    __shared__ float lfW[230], lfb[10], lsW[230], lsb[10];
    for (int i = threadIdx.x; i < 230; i += blockDim.x) { lfW[i] = fW[i]; lsW[i] = sW[i]; }
    for (int i = threadIdx.x; i < 10;  i += blockDim.x) { lfb[i] = fb[i]; lsb[i] = sb[i]; }
    __syncthreads();
    int n = blockIdx.x * blockDim.x + threadIdx.x;
    if (n >= N) return;
    float* hp = h + (size_t)n * DH;
    float* ap = agg + (size_t)n * DH;
    float hh[DH];
#pragma unroll
    for (int j = 0; j < DH; ++j) {
        hh[j] = fmaxf(hp[j] + ap[j], 0.f);
        hp[j] = hh[j];
        ap[j] = 0.f;
    }
    compute_records(hh, lfW, lfb, lsW, lsb, D + (size_t)n*REC, S + (size_t)n*REC);
}

__global__ void node_post(const float* __restrict__ h, const float* __restrict__ agg,
                          const int* __restrict__ batch,
                          float* __restrict__ gsum, float* __restrict__ gcnt, int N)
{
    int n = blockIdx.x * blockDim.x + threadIdx.x;
    if (n >= N) return;
    int b = batch[n];
    const float* hp = h + (size_t)n * DH;
    const float* ap = agg + (size_t)n * DH;
    float* gp = gsum + (size_t)b * DH;
#pragma unroll
    for (int j = 0; j < DH; ++j)
        atomicAdd(gp + j, fmaxf(hp[j] + ap[j], 0.f));
    atomicAdd(gcnt + b, 1.f);
}

// ---------------------------------------------------------------------------
// MLP head: one block (128 threads) per graph.
// ---------------------------------------------------------------------------
__global__ void mlp_head(const float* __restrict__ gsum, const float* __restrict__ gcnt,
                         const float* __restrict__ fc1W, const float* __restrict__ fc1b,
                         const float* __restrict__ fc2W, const float* __restrict__ fc2b,
                         const float* __restrict__ outW, const float* __restrict__ outb,
                         float* __restrict__ out, int G)
{
    __shared__ float g[DH], a1[128], a2[128];
    int gid = blockIdx.x;
    int t = threadIdx.x;
    if (t < DH) {
        float c = fmaxf(gcnt[gid], 1.0f);
        g[t] = gsum[(size_t)gid*DH + t] / c;
    }
    __syncthreads();
    {
        float acc = fc1b[t];
        const float* w = fc1W + (size_t)t * DH;
#pragma unroll
        for (int k = 0; k < DH; ++k) acc += w[k] * g[k];
        a1[t] = fmaxf(acc, 0.f);
    }
    __syncthreads();
    {
        float acc = fc2b[t];
        const float* w = fc2W + (size_t)t * 128;
#pragma unroll 8
        for (int k = 0; k < 128; ++k) acc += w[k] * a1[k];
        a2[t] = fmaxf(acc, 0.f);
    }
    __syncthreads();
    if (t < 3) {
        float acc = outb[t];
        const float* w = outW + (size_t)t * 128;
#pragma unroll 8
        for (int k = 0; k < 128; ++k) acc += w[k] * a2[k];
        out[(size_t)gid*3 + t] = acc;
    }
}

// ---------------------------------------------------------------------------
extern "C" void kernel_launch(void* const* d_in, const int* in_sizes, int n_in,
                              void* d_out, int out_size, void* d_ws, size_t ws_size,
                              hipStream_t stream)
{
    const float* x     = (const float*)d_in[0];
    const int*   ei    = (const int*)  d_in[1];
    const float* attr  = (const float*)d_in[2];
    const int*   batch = (const int*)  d_in[3];
    const float* preW  = (const float*)d_in[4];
    const float* preb  = (const float*)d_in[5];
    const float* f1W   = (const float*)d_in[6];
    const float* f1b   = (const float*)d_in[7];
    const float* s1W   = (const float*)d_in[8];
    const float* s1b   = (const float*)d_in[9];
    const float* f2W   = (const float*)d_in[10];
    const float* f2b   = (const float*)d_in[11];
    const float* s2W   = (const float*)d_in[12];
    const float* s2b   = (const float*)d_in[13];
    const float* fc1W  = (const float*)d_in[14];
    const float* fc1b  = (const float*)d_in[15];
    const float* fc2W  = (const float*)d_in[16];
    const float* fc2b  = (const float*)d_in[17];
    const float* outW  = (const float*)d_in[18];
    const float* outb  = (const float*)d_in[19];

    const int N = in_sizes[0] / DIN;      // 200000
    const int E = in_sizes[1] / 2;        // 6400000
    const int G = out_size / 3;           // 1024

    const int TB = 256;
    const int nb = (N + TB - 1) / TB;
    const int eb = (E + TB - 1) / TB;
    const int gb = (N * VEC + TB - 1) / TB;

    // ---- CSR-path workspace layout ----
    size_t f_off = 0;
    float* ws = (float*)d_ws;
    float* h    = ws + f_off; f_off += (size_t)N * DH;
    float* D    = ws + f_off; f_off += (size_t)N * REC;
    u32*   Sh   = (u32*)(ws + f_off); f_off += (size_t)N * SHU;   // 48B/node fp16 recs
    float* gsum = ws + f_off; f_off += (size_t)G * DH;
    float* gcnt = ws + f_off; f_off += G;
    f_off = (f_off + 15) & ~(size_t)15;
    int* rowptr = (int*)(ws + f_off); f_off += N + 1;
    int* head   = (int*)(ws + f_off); f_off += N;
    int* deg    = (int*)(ws + f_off); f_off += N;
    int* bsum   = (int*)(ws + f_off); f_off += nb;
    f_off = (f_off + 15) & ~(size_t)15;
    float4* csr = (float4*)(ws + f_off);
    size_t need = (f_off + (size_t)E * 4) * sizeof(float);

    if (need <= ws_size) {
        // ===== CSR path =====
        node_pre_h<<<nb, TB, 0, stream>>>(x, preW, preb, f1W, f1b, s1W, s1b,
                                          h, D, Sh, deg, gsum, gcnt, N, G);
        hist_kernel<<<eb, TB, 0, stream>>>(ei, deg, E);
        scan_block<<<nb, TB, 0, stream>>>(deg, rowptr, bsum, N);
        scan_sums<<<1, 1024, 0, stream>>>(bsum, nb);
        scan_add<<<nb, TB, 0, stream>>>(rowptr, bsum, head, N, E);
        scatter_csr<<<eb, TB, 0, stream>>>(ei, attr, head, csr, E);

        gather_agg4<<<gb, TB, 0, stream>>>(rowptr, csr, D, Sh, f1W, s1W, h, N,
                                           nullptr, nullptr, nullptr, 0);
        node_rec_h<<<nb, TB, 0, stream>>>(h, f2W, f2b, s2W, s2b, D, Sh, N);
        gather_agg4<<<gb, TB, 0, stream>>>(rowptr, csr, D, Sh, f2W, s2W, h, N,
                                           batch, gsum, gcnt, 1);
        mlp_head<<<G, 128, 0, stream>>>(gsum, gcnt, fc1W, fc1b, fc2W, fc2b,
                                        outW, outb, (float*)d_out, G);
    } else {
        // ===== fallback: fp32 atomic path =====
        size_t o = 0;
        float* fh    = ws + o; o += (size_t)N * DH;
        float* agg   = ws + o; o += (size_t)N * DH;
        float* fD    = ws + o; o += (size_t)N * REC;
        float* fS    = ws + o; o += (size_t)N * REC;
        float* fgsum = ws + o; o += (size_t)G * DH;
        float* fgcnt = ws + o; o += G;

        node_pre_f32<<<nb, TB, 0, stream>>>(x, preW, preb, f1W, f1b, s1W, s1b,
                                            fh, fD, fS, agg, fgsum, fgcnt, N, G);
        edge_pass<<<eb, TB, 0, stream>>>(ei, attr, fD, fS, f1W, s1W, agg, E);
        node_mid<<<nb, TB, 0, stream>>>(fh, agg, f2W, f2b, s2W, s2b, fD, fS, N);
        edge_pass<<<eb, TB, 0, stream>>>(ei, attr, fD, fS, f2W, s2W, agg, E);
        node_post<<<nb, TB, 0, stream>>>(fh, agg, batch, fgsum, fgcnt, N);
        mlp_head<<<G, 128, 0, stream>>>(fgsum, fgcnt, fc1W, fc1b, fc2W, fc2b,
                                        outW, outb, (float*)d_out, G);
    }
}

// Round 6
// 1541.116 us; speedup vs baseline: 1.0942x; 1.0942x over previous
//
#include <hip/hip_runtime.h>
#include <hip/hip_bf16.h>
#include <hip/hip_fp16.h>
#include <math.h>

#define DH 10      // hidden dim
#define DE 3       // edge attr dim
#define DIN 3      // input dim
#define REC 20     // fp32 D record: 20 floats = 80B
#define SHU 12     // fp16 S record stride in uints (24 halves = 48B, 10 used)
#define VEC 4      // lanes cooperating per node in gather
#define NR 8       // src ranges for L2 locality (N/8 nodes * 48B ~ 1.2MB per range)

typedef unsigned int u32;
typedef float f4v __attribute__((ext_vector_type(4)));

__device__ __forceinline__ u32 pack_h2(float a, float b) {
    union { __half2 h; u32 u; } cv;
    cv.h = __floats2half2_rn(a, b);
    return cv.u;
}

// ---------------------------------------------------------------------------
// Per-node records. D (fp32, dst side, biases folded): {fb + h@fWd.T, sb + h@sWd.T}
// S (fp16 packed, src side): {h@fWs.T, h@sWs.T} as 10 half2 words.
// ---------------------------------------------------------------------------
__device__ __forceinline__ void compute_records_h(
    const float* __restrict__ hh,
    const float* __restrict__ fW, const float* __restrict__ fb,
    const float* __restrict__ sW, const float* __restrict__ sb,
    float* __restrict__ Dout, u32* __restrict__ Sout)
{
    float fsv[DH], ssv[DH];
#pragma unroll
    for (int j = 0; j < DH; ++j) {
        float fd = fb[j], sd = sb[j], fs = 0.f, ss = 0.f;
#pragma unroll
        for (int k = 0; k < DH; ++k) {
            fd += hh[k] * fW[j*23 + k];
            fs += hh[k] * fW[j*23 + 10 + k];
            sd += hh[k] * sW[j*23 + k];
            ss += hh[k] * sW[j*23 + 10 + k];
        }
        Dout[j]      = fd;
        Dout[DH + j] = sd;
        fsv[j] = fs;
        ssv[j] = ss;
    }
#pragma unroll
    for (int j = 0; j < 5; ++j) {
        Sout[j]     = pack_h2(fsv[2*j], fsv[2*j+1]);
        Sout[5 + j] = pack_h2(ssv[2*j], ssv[2*j+1]);
    }
}

// fp32 variant for the fallback path
__device__ __forceinline__ void compute_records(
    const float* __restrict__ hh,
    const float* __restrict__ fW, const float* __restrict__ fb,
    const float* __restrict__ sW, const float* __restrict__ sb,
    float* __restrict__ Dout, float* __restrict__ Sout)
{
#pragma unroll
    for (int j = 0; j < DH; ++j) {
        float fd = fb[j], sd = sb[j], fs = 0.f, ss = 0.f;
#pragma unroll
        for (int k = 0; k < DH; ++k) {
            fd += hh[k] * fW[j*23 + k];
            fs += hh[k] * fW[j*23 + 10 + k];
            sd += hh[k] * sW[j*23 + k];
            ss += hh[k] * sW[j*23 + 10 + k];
        }
        Dout[j]      = fd;
        Dout[DH + j] = sd;
        Sout[j]      = fs;
        Sout[DH + j] = ss;
    }
}

// ---------------------------------------------------------------------------
// P0 (csr path): h0 = relu(x@preW.T+preb); layer-1 records; zero deg8/gsum/gcnt
// ---------------------------------------------------------------------------
__global__ void node_pre_h(const float* __restrict__ x,
                           const float* __restrict__ preW, const float* __restrict__ preb,
                           const float* __restrict__ fW, const float* __restrict__ fb,
                           const float* __restrict__ sW, const float* __restrict__ sb,
                           float* __restrict__ h, float* __restrict__ D, u32* __restrict__ Sh,
                           int* __restrict__ deg8,
                           float* __restrict__ gsum, float* __restrict__ gcnt, int N, int G)
{
    __shared__ float lpW[30], lpb[10], lfW[230], lfb[10], lsW[230], lsb[10];
    for (int i = threadIdx.x; i < 30;  i += blockDim.x) lpW[i] = preW[i];
    for (int i = threadIdx.x; i < 10;  i += blockDim.x) { lpb[i] = preb[i]; lfb[i] = fb[i]; lsb[i] = sb[i]; }
    for (int i = threadIdx.x; i < 230; i += blockDim.x) { lfW[i] = fW[i]; lsW[i] = sW[i]; }
    __syncthreads();

    int n = blockIdx.x * blockDim.x + threadIdx.x;
    if (n < G * DH) gsum[n] = 0.f;
    if (n < G)      gcnt[n] = 0.f;
    if (n >= N) return;
    int4* d8 = (int4*)(deg8 + (size_t)n * NR);
    d8[0] = make_int4(0,0,0,0);
    d8[1] = make_int4(0,0,0,0);

    float x0 = x[(size_t)n*3], x1 = x[(size_t)n*3+1], x2 = x[(size_t)n*3+2];
    float hh[DH];
#pragma unroll
    for (int j = 0; j < DH; ++j)
        hh[j] = fmaxf(lpb[j] + x0*lpW[j*3] + x1*lpW[j*3+1] + x2*lpW[j*3+2], 0.f);

    float* hp = h + (size_t)n * DH;
#pragma unroll
    for (int j = 0; j < DH; ++j) hp[j] = hh[j];

    compute_records_h(hh, lfW, lfb, lsW, lsb, D + (size_t)n*REC, Sh + (size_t)n*SHU);
}

// ---------------------------------------------------------------------------
// CSR build, range-bucketed: hist8 -> scan (summing 8 buckets/node) -> head8
// (per-node cumsum, in place) -> scatter8
// ---------------------------------------------------------------------------
__global__ void hist8(const int* __restrict__ ei, int* __restrict__ deg8, int E, int RS)
{
    int e = blockIdx.x * blockDim.x + threadIdx.x;
    if (e >= E) return;
    int src = __builtin_nontemporal_load(ei + e);
    int dst = __builtin_nontemporal_load(ei + (size_t)E + e);
    int r = src / RS;                       // 0..NR-1
    atomicAdd(&deg8[(size_t)dst * NR + r], 1);
}

__global__ void scan_block(const int* __restrict__ deg8, int* __restrict__ excl,
                           int* __restrict__ bsum, int N)
{
    __shared__ int s[256];
    int tid = threadIdx.x;
    int n = blockIdx.x * 256 + tid;
    int v = 0;
    if (n < N) {
        const int4* d8 = (const int4*)(deg8 + (size_t)n * NR);
        int4 a = d8[0], b = d8[1];
        v = a.x + a.y + a.z + a.w + b.x + b.y + b.z + b.w;
    }
    s[tid] = v;
    __syncthreads();
#pragma unroll
    for (int off = 1; off < 256; off <<= 1) {
        int t = (tid >= off) ? s[tid - off] : 0;
        __syncthreads();
        if (tid >= off) s[tid] += t;
        __syncthreads();
    }
    if (n < N) excl[n] = s[tid] - v;
    if (tid == 255) bsum[blockIdx.x] = s[255];
}

__global__ void scan_sums(int* __restrict__ bsum, int B)   // exclusive, in place
{
    __shared__ int s[1024];
    int tid = threadIdx.x;
    int v = (tid < B) ? bsum[tid] : 0;
    s[tid] = v;
    __syncthreads();
#pragma unroll
    for (int off = 1; off < 1024; off <<= 1) {
        int t = (tid >= off) ? s[tid - off] : 0;
        __syncthreads();
        if (tid >= off) s[tid] += t;
        __syncthreads();
    }
    if (tid < B) bsum[tid] = s[tid] - v;
}

__global__ void scan_add(int* __restrict__ rowptr, const int* __restrict__ bsum,
                         int N, int E)
{
    int n = blockIdx.x * blockDim.x + threadIdx.x;
    if (n < N) rowptr[n] += bsum[n >> 8];
    if (n == 0) rowptr[N] = E;
}

// per-node cumsum over the 8 range counts; deg8 becomes head8 in place
__global__ void head8_k(const int* __restrict__ rowptr, int* __restrict__ deg8, int N)
{
    int n = blockIdx.x * blockDim.x + threadIdx.x;
    if (n >= N) return;
    int base = rowptr[n];
    int* d = deg8 + (size_t)n * NR;
#pragma unroll
    for (int r = 0; r < NR; ++r) {
        int c = d[r];
        d[r] = base;
        base += c;
    }
}

__global__ void scatter8(const int* __restrict__ ei, const float* __restrict__ attr,
                         int* __restrict__ head8, float4* __restrict__ csr, int E, int RS)
{
    int e = blockIdx.x * blockDim.x + threadIdx.x;
    if (e >= E) return;
    int src = __builtin_nontemporal_load(ei + e);
    int dst = __builtin_nontemporal_load(ei + (size_t)E + e);
    float a0 = __builtin_nontemporal_load(attr + (size_t)e * DE);
    float a1 = __builtin_nontemporal_load(attr + (size_t)e * DE + 1);
    float a2 = __builtin_nontemporal_load(attr + (size_t)e * DE + 2);
    int r = src / RS;
    int pos = atomicAdd(&head8[(size_t)dst * NR + r], 1);
    csr[pos] = make_float4(__int_as_float(src), a0, a1, a2);
}

// ---------------------------------------------------------------------------
// Gather aggregation (R4 structure: strided VEC=4, 2-edge pipeline, fp16 srec).
// Edges per node are src-range-sorted -> resident waves walk the S-table
// range by range; active working set ~1-2 ranges (<=2.4MB) fits per-XCD L2.
// ---------------------------------------------------------------------------
struct SRecP { uint4 A, B; uint2 C; };

__device__ __forceinline__ SRecP load_srec(const u32* __restrict__ ShU, int src)
{
    const uint4* sp = (const uint4*)(ShU + (size_t)src * SHU);
    SRecP r;
    r.A = sp[0];
    r.B = sp[1];
    r.C = *(const uint2*)(sp + 2);
    return r;
}

__device__ __forceinline__ void compute_edge(
    f4v c, const SRecP& r, const float* __restrict__ drec,
    const float* __restrict__ wf, const float* __restrict__ wsr,
    float* __restrict__ acc)
{
    u32 u[10] = {r.A.x, r.A.y, r.A.z, r.A.w, r.B.x, r.B.y, r.B.z, r.B.w, r.C.x, r.C.y};
    float s[20];
#pragma unroll
    for (int i = 0; i < 10; ++i) {
        union { u32 u; __half2 h; } cv; cv.u = u[i];
        float2 f = __half22float2(cv.h);
        s[2*i] = f.x; s[2*i+1] = f.y;
    }
#pragma unroll
    for (int j = 0; j < DH; ++j) {
        float pf = drec[j]      + s[j]      + c.y*wf[j*3]  + c.z*wf[j*3+1]  + c.w*wf[j*3+2];
        float ps = drec[DH + j] + s[DH + j] + c.y*wsr[j*3] + c.z*wsr[j*3+1] + c.w*wsr[j*3+2];
        float sg = __builtin_amdgcn_rcpf(1.0f + __expf(-pf));          // sigmoid
        float sp = fmaxf(ps, 0.f) + __logf(1.0f + __expf(-fabsf(ps))); // softplus
        acc[j] += sg * sp;
    }
}

__global__ __launch_bounds__(256) void gather_agg4(
    const int* __restrict__ rowptr, const float4* __restrict__ csr,
    const float* __restrict__ D, const u32* __restrict__ ShU,
    const float* __restrict__ Wf, const float* __restrict__ Ws,
    float* __restrict__ h, int N,
    const int* __restrict__ batch,
    float* __restrict__ gsum, float* __restrict__ gcnt, int do_pool)
{
    // uniform edge-column weights -> scalar (SGPR) after unroll
    float wf[30], wsr[30];
#pragma unroll
    for (int i = 0; i < 30; ++i) {
        int j = i / 3, t = i % 3;
        wf[i]  = Wf[j*23 + 20 + t];
        wsr[i] = Ws[j*23 + 20 + t];
    }

    int tid = blockIdx.x * blockDim.x + threadIdx.x;
    int n   = tid >> 2;
    int sub = tid & (VEC - 1);
    if (n >= N) return;

    float drec[REC];
    const float4* Dp = (const float4*)(D + (size_t)n * REC);
#pragma unroll
    for (int i = 0; i < 5; ++i) ((float4*)drec)[i] = Dp[i];

    float acc[DH];
#pragma unroll
    for (int j = 0; j < DH; ++j) acc[j] = 0.f;

    const f4v* cp = (const f4v*)csr;
    int p  = rowptr[n] + sub;
    int p1 = rowptr[n + 1];

    // 2-edge pipeline, strided so all lanes stay in the same src-range
    for (; p + VEC < p1; p += 2 * VEC) {
        f4v c0 = __builtin_nontemporal_load(cp + p);
        f4v c1 = __builtin_nontemporal_load(cp + p + VEC);
        SRecP r0 = load_srec(ShU, __float_as_int(c0.x));
        SRecP r1 = load_srec(ShU, __float_as_int(c1.x));
        compute_edge(c0, r0, drec, wf, wsr, acc);
        compute_edge(c1, r1, drec, wf, wsr, acc);
    }
    if (p < p1) {
        f4v c0 = __builtin_nontemporal_load(cp + p);
        SRecP r0 = load_srec(ShU, __float_as_int(c0.x));
        compute_edge(c0, r0, drec, wf, wsr, acc);
    }

    // butterfly reduce across the 4 lanes of this node
#pragma unroll
    for (int j = 0; j < DH; ++j) {
        acc[j] += __shfl_xor(acc[j], 1);
        acc[j] += __shfl_xor(acc[j], 2);
    }

    if (sub == 0) {
        float* hp = h + (size_t)n * DH;
        float hh[DH];
#pragma unroll
        for (int j = 0; j < DH; ++j) hh[j] = fmaxf(hp[j] + acc[j], 0.f);
        if (do_pool) {
            int b = batch[n];
            float* gp = gsum + (size_t)b * DH;
#pragma unroll
            for (int j = 0; j < DH; ++j) atomicAdd(gp + j, hh[j]);
            atomicAdd(gcnt + b, 1.f);
        } else {
#pragma unroll
            for (int j = 0; j < DH; ++j) hp[j] = hh[j];
        }
    }
}

// Records for layer 2 from h1
__global__ void node_rec_h(const float* __restrict__ h,
                           const float* __restrict__ fW, const float* __restrict__ fb,
                           const float* __restrict__ sW, const float* __restrict__ sb,
                           float* __restrict__ D, u32* __restrict__ Sh, int N)
{
    __shared__ float lfW[230], lfb[10], lsW[230], lsb[10];
    for (int i = threadIdx.x; i < 230; i += blockDim.x) { lfW[i] = fW[i]; lsW[i] = sW[i]; }
    for (int i = threadIdx.x; i < 10;  i += blockDim.x) { lfb[i] = fb[i]; lsb[i] = sb[i]; }
    __syncthreads();
    int n = blockIdx.x * blockDim.x + threadIdx.x;
    if (n >= N) return;
    float hh[DH];
    const float* hp = h + (size_t)n * DH;
#pragma unroll
    for (int j = 0; j < DH; ++j) hh[j] = hp[j];
    compute_records_h(hh, lfW, lfb, lsW, lsb, D + (size_t)n*REC, Sh + (size_t)n*SHU);
}

// ---------------------------------------------------------------------------
// Fallback path kernels (fp32 everything; used only if ws too small)
// ---------------------------------------------------------------------------
__global__ void node_pre_f32(const float* __restrict__ x,
                             const float* __restrict__ preW, const float* __restrict__ preb,
                             const float* __restrict__ fW, const float* __restrict__ fb,
                             const float* __restrict__ sW, const float* __restrict__ sb,
                             float* __restrict__ h, float* __restrict__ D, float* __restrict__ S,
                             float* __restrict__ agg,
                             float* __restrict__ gsum, float* __restrict__ gcnt, int N, int G)
{
    __shared__ float lpW[30], lpb[10], lfW[230], lfb[10], lsW[230], lsb[10];
    for (int i = threadIdx.x; i < 30;  i += blockDim.x) lpW[i] = preW[i];
    for (int i = threadIdx.x; i < 10;  i += blockDim.x) { lpb[i] = preb[i]; lfb[i] = fb[i]; lsb[i] = sb[i]; }
    for (int i = threadIdx.x; i < 230; i += blockDim.x) { lfW[i] = fW[i]; lsW[i] = sW[i]; }
    __syncthreads();
    int n = blockIdx.x * blockDim.x + threadIdx.x;
    if (n < G * DH) gsum[n] = 0.f;
    if (n < G)      gcnt[n] = 0.f;
    if (n >= N) return;
    float x0 = x[(size_t)n*3], x1 = x[(size_t)n*3+1], x2 = x[(size_t)n*3+2];
    float hh[DH];
#pragma unroll
    for (int j = 0; j < DH; ++j)
        hh[j] = fmaxf(lpb[j] + x0*lpW[j*3] + x1*lpW[j*3+1] + x2*lpW[j*3+2], 0.f);
    float* hp = h + (size_t)n * DH;
    float* ap = agg + (size_t)n * DH;
#pragma unroll
    for (int j = 0; j < DH; ++j) { hp[j] = hh[j]; ap[j] = 0.f; }
    compute_records(hh, lfW, lfb, lsW, lsb, D + (size_t)n*REC, S + (size_t)n*REC);
}

__global__ void edge_pass(const int* __restrict__ ei, const float* __restrict__ attr,
                          const float* __restrict__ D, const float* __restrict__ S,
                          const float* __restrict__ Wf, const float* __restrict__ Ws,
                          float* __restrict__ agg, int E)
{
    __shared__ float wfe[30], wse[30];
    if (threadIdx.x < 30) {
        int j = threadIdx.x / 3, t = threadIdx.x % 3;
        wfe[threadIdx.x] = Wf[j*23 + 20 + t];
        wse[threadIdx.x] = Ws[j*23 + 20 + t];
    }
    __syncthreads();
    int e = blockIdx.x * blockDim.x + threadIdx.x;
    if (e >= E) return;
    int src = ei[e];
    int dst = ei[(size_t)E + e];
    const float* eap = attr + (size_t)e * DE;
    float ea0 = eap[0], ea1 = eap[1], ea2 = eap[2];
    float drec[REC], srec[REC];
    const float4* Dp = (const float4*)(D + (size_t)dst * REC);
    const float4* Sp = (const float4*)(S + (size_t)src * REC);
#pragma unroll
    for (int i = 0; i < 5; ++i) { ((float4*)drec)[i] = Dp[i]; ((float4*)srec)[i] = Sp[i]; }
    float* ap = agg + (size_t)dst * DH;
#pragma unroll
    for (int j = 0; j < DH; ++j) {
        float pf = drec[j]      + srec[j]      + ea0*wfe[j*3] + ea1*wfe[j*3+1] + ea2*wfe[j*3+2];
        float ps = drec[DH + j] + srec[DH + j] + ea0*wse[j*3] + ea1*wse[j*3+1] + ea2*wse[j*3+2];
        float sg = 1.0f / (1.0f + __expf(-pf));
        float sp = fmaxf(ps, 0.f) + log1pf(__expf(-fabsf(ps)));
        atomicAdd(ap + j, sg * sp);
    }
}

__global__ void node_mid(float* __restrict__ h, float* __restrict__ agg,
                         const float* __restrict__ fW, const float* __restrict__ fb,
                         const float* __restrict__ sW, const float* __restrict__ sb,
                         float* __restrict__ D, float* __restrict__ S, int N)
{
    __shared__ float lfW[230], lfb[10], lsW[230], lsb[10];
    for (int i = threadIdx.x; i < 230; i += blockDim.x) { lfW[i] = fW[i]; lsW[i] = sW[i]; }
    for (int i = threadIdx.x; i < 10;  i += blockDim.x) { lfb[i] = fb[i]; lsb[i] = sb[i]; }
    __syncthreads();
    int n = blockIdx.x * blockDim.x + threadIdx.x;
    if (n >= N) return;
    float* hp = h + (size_t)n * DH;
    float* ap = agg + (size_t)n * DH;
    float hh[DH];
#pragma unroll
    for (int j = 0; j < DH; ++j) {
        hh[j] = fmaxf(hp[j] + ap[j], 0.f);
        hp[j] = hh[j];
        ap[j] = 0.f;
    }
    compute_records(hh, lfW, lfb, lsW, lsb, D + (size_t)n*REC, S + (size_t)n*REC);
}

__global__ void node_post(const float* __restrict__ h, const float* __restrict__ agg,
                          const int* __restrict__ batch,
                          float* __restrict__ gsum, float* __restrict__ gcnt, int N)
{
    int n = blockIdx.x * blockDim.x + threadIdx.x;
    if (n >= N) return;
    int b = batch[n];
    const float* hp = h + (size_t)n * DH;
    const float* ap = agg + (size_t)n * DH;
    float* gp = gsum + (size_t)b * DH;
#pragma unroll
    for (int j = 0; j < DH; ++j)
        atomicAdd(gp + j, fmaxf(hp[j] + ap[j], 0.f));
    atomicAdd(gcnt + b, 1.f);
}

// ---------------------------------------------------------------------------
// MLP head: one block (128 threads) per graph.
// ---------------------------------------------------------------------------
__global__ void mlp_head(const float* __restrict__ gsum, const float* __restrict__ gcnt,
                         const float* __restrict__ fc1W, const float* __restrict__ fc1b,
                         const float* __restrict__ fc2W, const float* __restrict__ fc2b,
                         const float* __restrict__ outW, const float* __restrict__ outb,
                         float* __restrict__ out, int G)
{
    __shared__ float g[DH], a1[128], a2[128];
    int gid = blockIdx.x;
    int t = threadIdx.x;
    if (t < DH) {
        float c = fmaxf(gcnt[gid], 1.0f);
        g[t] = gsum[(size_t)gid*DH + t] / c;
    }
    __syncthreads();
    {
        float acc = fc1b[t];
        const float* w = fc1W + (size_t)t * DH;
#pragma unroll
        for (int k = 0; k < DH; ++k) acc += w[k] * g[k];
        a1[t] = fmaxf(acc, 0.f);
    }
    __syncthreads();
    {
        float acc = fc2b[t];
        const float* w = fc2W + (size_t)t * 128;
#pragma unroll 8
        for (int k = 0; k < 128; ++k) acc += w[k] * a1[k];
        a2[t] = fmaxf(acc, 0.f);
    }
    __syncthreads();
    if (t < 3) {
        float acc = outb[t];
        const float* w = outW + (size_t)t * 128;
#pragma unroll 8
        for (int k = 0; k < 128; ++k) acc += w[k] * a2[k];
        out[(size_t)gid*3 + t] = acc;
    }
}

// ---------------------------------------------------------------------------
extern "C" void kernel_launch(void* const* d_in, const int* in_sizes, int n_in,
                              void* d_out, int out_size, void* d_ws, size_t ws_size,
                              hipStream_t stream)
{
    const float* x     = (const float*)d_in[0];
    const int*   ei    = (const int*)  d_in[1];
    const float* attr  = (const float*)d_in[2];
    const int*   batch = (const int*)  d_in[3];
    const float* preW  = (const float*)d_in[4];
    const float* preb  = (const float*)d_in[5];
    const float* f1W   = (const float*)d_in[6];
    const float* f1b   = (const float*)d_in[7];
    const float* s1W   = (const float*)d_in[8];
    const float* s1b   = (const float*)d_in[9];
    const float* f2W   = (const float*)d_in[10];
    const float* f2b   = (const float*)d_in[11];
    const float* s2W   = (const float*)d_in[12];
    const float* s2b   = (const float*)d_in[13];
    const float* fc1W  = (const float*)d_in[14];
    const float* fc1b  = (const float*)d_in[15];
    const float* fc2W  = (const float*)d_in[16];
    const float* fc2b  = (const float*)d_in[17];
    const float* outW  = (const float*)d_in[18];
    const float* outb  = (const float*)d_in[19];

    const int N = in_sizes[0] / DIN;      // 200000
    const int E = in_sizes[1] / 2;        // 6400000
    const int G = out_size / 3;           // 1024
    const int RS = (N + NR - 1) / NR;     // nodes per src-range

    const int TB = 256;
    const int nb = (N + TB - 1) / TB;
    const int eb = (E + TB - 1) / TB;
    const int gb = (N * VEC + TB - 1) / TB;

    // ---- CSR-path workspace layout ----
    size_t f_off = 0;
    float* ws = (float*)d_ws;
    float* h    = ws + f_off; f_off += (size_t)N * DH;
    float* D    = ws + f_off; f_off += (size_t)N * REC;
    u32*   Sh   = (u32*)(ws + f_off); f_off += (size_t)N * SHU;   // 48B/node fp16 recs
    float* gsum = ws + f_off; f_off += (size_t)G * DH;
    float* gcnt = ws + f_off; f_off += G;
    f_off = (f_off + 15) & ~(size_t)15;
    int* rowptr = (int*)(ws + f_off); f_off += N + 1;
    int* bsum   = (int*)(ws + f_off); f_off += nb;
    f_off = (f_off + 3) & ~(size_t)3;
    int* deg8   = (int*)(ws + f_off); f_off += (size_t)N * NR;    // also head8 (in place)
    f_off = (f_off + 15) & ~(size_t)15;
    float4* csr = (float4*)(ws + f_off);
    size_t need = (f_off + (size_t)E * 4) * sizeof(float);

    if (need <= ws_size) {
        // ===== CSR path (range-bucketed) =====
        node_pre_h<<<nb, TB, 0, stream>>>(x, preW, preb, f1W, f1b, s1W, s1b,
                                          h, D, Sh, deg8, gsum, gcnt, N, G);
        hist8<<<eb, TB, 0, stream>>>(ei, deg8, E, RS);
        scan_block<<<nb, TB, 0, stream>>>(deg8, rowptr, bsum, N);
        scan_sums<<<1, 1024, 0, stream>>>(bsum, nb);
        scan_add<<<nb, TB, 0, stream>>>(rowptr, bsum, N, E);
        head8_k<<<nb, TB, 0, stream>>>(rowptr, deg8, N);
        scatter8<<<eb, TB, 0, stream>>>(ei, attr, deg8, csr, E, RS);

        gather_agg4<<<gb, TB, 0, stream>>>(rowptr, csr, D, Sh, f1W, s1W, h, N,
                                           nullptr, nullptr, nullptr, 0);
        node_rec_h<<<nb, TB, 0, stream>>>(h, f2W, f2b, s2W, s2b, D, Sh, N);
        gather_agg4<<<gb, TB, 0, stream>>>(rowptr, csr, D, Sh, f2W, s2W, h, N,
                                           batch, gsum, gcnt, 1);
        mlp_head<<<G, 128, 0, stream>>>(gsum, gcnt, fc1W, fc1b, fc2W, fc2b,
                                        outW, outb, (float*)d_out, G);
    } else {
        // ===== fallback: fp32 atomic path =====
        size_t o = 0;
        float* fh    = ws + o; o += (size_t)N * DH;
        float* agg   = ws + o; o += (size_t)N * DH;
        float* fD    = ws + o; o += (size_t)N * REC;
        float* fS    = ws + o; o += (size_t)N * REC;
        float* fgsum = ws + o; o += (size_t)G * DH;
        float* fgcnt = ws + o; o += G;

        node_pre_f32<<<nb, TB, 0, stream>>>(x, preW, preb, f1W, f1b, s1W, s1b,
                                            fh, fD, fS, agg, fgsum, fgcnt, N, G);
        edge_pass<<<eb, TB, 0, stream>>>(ei, attr, fD, fS, f1W, s1W, agg, E);
        node_mid<<<nb, TB, 0, stream>>>(fh, agg, f2W, f2b, s2W, s2b, fD, fS, N);
        edge_pass<<<eb, TB, 0, stream>>>(ei, attr, fD, fS, f2W, s2W, agg, E);
        node_post<<<nb, TB, 0, stream>>>(fh, agg, batch, fgsum, fgcnt, N);
        mlp_head<<<G, 128, 0, stream>>>(fgsum, fgcnt, fc1W, fc1b, fc2W, fc2b,
                                        outW, outb, (float*)d_out, G);
    }
}